// Round 4
// baseline (283.776 us; speedup 1.0000x reference)
//
#include <hip/hip_runtime.h>
#include <math.h>
#include <stdint.h>

#define T_LEN   2048
#define D_MODEL 1024
#define NH      16
#define DFF     4096

typedef __attribute__((ext_vector_type(8))) short bf16x8;
typedef __attribute__((ext_vector_type(4))) float f32x4;
typedef __attribute__((ext_vector_type(4))) unsigned short u16x4;
typedef __attribute__((ext_vector_type(8))) unsigned short u16x8;
typedef unsigned short u16;

__device__ inline u16 f2b(float x) {
  unsigned int u = __float_as_uint(x);
  unsigned int r = (u + 0x7fffu + ((u >> 16) & 1u)) >> 16;
  return (u16)r;
}
__device__ inline float b2f(u16 h) { return __uint_as_float(((unsigned int)h) << 16); }

typedef const __attribute__((address_space(1))) unsigned int* gas_t;
typedef __attribute__((address_space(3))) unsigned int* las_t;
__device__ inline void gl_lds16(const void* g, void* l) {
  __builtin_amdgcn_global_load_lds((gas_t)g, (las_t)l, 16, 0, 0);
}

#define MFMA16(a, b, c) __builtin_amdgcn_mfma_f32_16x16x32_bf16((a), (b), (c), 0, 0, 0)
#define VMCNT(N) asm volatile("s_waitcnt vmcnt(" #N ")" ::: "memory")

// ---------------------------------------------------------------------------
// merged weight prep: 6 convert segments in one dispatch.  grid (1024,1,6)
// ---------------------------------------------------------------------------
__global__ __launch_bounds__(256) void prep_conv_kernel(
    const float* s0, const float* s1, const float* s2, const float* s3,
    const float* s4, const float* s5,
    u16* d0, u16* d1, u16* d2, u16* d3, u16* d4, u16* d5) {
  int z = blockIdx.z;
  const float* s; u16* d; int n4;
  switch (z) {
    case 0: s = s0; d = d0; n4 = 262144; break;
    case 1: s = s1; d = d1; n4 = 262144; break;
    case 2: s = s2; d = d2; n4 = 262144; break;
    case 3: s = s3; d = d3; n4 = 262144; break;
    case 4: s = s4; d = d4; n4 = 262144; break;
    default: s = s5; d = d5; n4 = 65536; break;
  }
  int i = blockIdx.x * 256 + threadIdx.x;
  if (i < n4) {
    float4 v = reinterpret_cast<const float4*>(s)[i];
    u16x4 o = {f2b(v.x), f2b(v.y), f2b(v.z), f2b(v.w)};
    reinterpret_cast<u16x4*>(d)[i] = o;
  }
}

// ---------------------------------------------------------------------------
// transpose+convert: w[h][K][64] f32 -> wt[h*64+c][K] bf16.  grid (K/64, 4)
// ---------------------------------------------------------------------------
__global__ __launch_bounds__(256) void tr_kernel(
    const float* __restrict__ w, u16* __restrict__ wt, int K) {
  int k0 = blockIdx.x * 64, h = blockIdx.y;
  __shared__ float Ts[64][65];
  int tid = threadIdx.x;
#pragma unroll
  for (int i = 0; i < 4; ++i) {
    int idx = tid + i * 256;
    int r = idx >> 4, c4 = (idx & 15) * 4;
    float4 v = *reinterpret_cast<const float4*>(w + ((size_t)h * K + k0 + r) * 64 + c4);
    Ts[r][c4 + 0] = v.x; Ts[r][c4 + 1] = v.y; Ts[r][c4 + 2] = v.z; Ts[r][c4 + 3] = v.w;
  }
  __syncthreads();
#pragma unroll
  for (int i = 0; i < 4; ++i) {
    int idx = tid + i * 256;
    int c = idx >> 4, k4 = (idx & 15) * 4;
    u16x4 o = {f2b(Ts[k4 + 0][c]), f2b(Ts[k4 + 1][c]), f2b(Ts[k4 + 2][c]), f2b(Ts[k4 + 3][c])};
    *reinterpret_cast<u16x4*>(wt + (size_t)(h * 64 + c) * K + k0 + k4) = o;
  }
}

// ---------------------------------------------------------------------------
// V transpose: V[t][1024] bf16 -> VT[h*64+d][2048] bf16.  grid (T/64, 16)
// ---------------------------------------------------------------------------
__global__ __launch_bounds__(256) void vtrans_kernel(
    const u16* __restrict__ V, u16* __restrict__ VT) {
  __shared__ u16 Ts[64][72];
  int t0 = blockIdx.x * 64, h = blockIdx.y;
  int tid = threadIdx.x;
#pragma unroll
  for (int it = 0; it < 2; ++it) {
    int c = tid + it * 256;
    int t = c >> 3, d8 = (c & 7) * 8;
    *reinterpret_cast<u16x8*>(&Ts[t][d8]) =
        *reinterpret_cast<const u16x8*>(V + (size_t)(t0 + t) * D_MODEL + h * 64 + d8);
  }
  __syncthreads();
#pragma unroll
  for (int it = 0; it < 2; ++it) {
    int c = tid + it * 256;
    int d = c >> 3, t8 = (c & 7) * 8;
    u16x8 o;
#pragma unroll
    for (int j = 0; j < 8; ++j) o[j] = Ts[t8 + j][d];
    *reinterpret_cast<u16x8*>(VT + ((size_t)h * 64 + d) * T_LEN + t0 + t8) = o;
  }
}

// ---------------------------------------------------------------------------
// RMS f32-in -> bf16 (optional weight)
// ---------------------------------------------------------------------------
template <int NV, bool WEIGHT>
__global__ __launch_bounds__(256) void rms_bf16_kernel(
    const float* __restrict__ in, const float* __restrict__ w,
    u16* __restrict__ out, int width) {
  int row = blockIdx.x, tid = threadIdx.x;
  const float* rp = in + (size_t)row * width;
  float4 vals[NV];
  float ss = 0.f;
#pragma unroll
  for (int v = 0; v < NV; ++v) {
    vals[v] = reinterpret_cast<const float4*>(rp)[v * 256 + tid];
    ss += vals[v].x * vals[v].x + vals[v].y * vals[v].y +
          vals[v].z * vals[v].z + vals[v].w * vals[v].w;
  }
  for (int off = 32; off; off >>= 1) ss += __shfl_down(ss, off, 64);
  __shared__ float wsum[4];
  if ((tid & 63) == 0) wsum[tid >> 6] = ss;
  __syncthreads();
  float tot = wsum[0] + wsum[1] + wsum[2] + wsum[3];
  float scale = rsqrtf(tot / (float)width + 1e-6f);
#pragma unroll
  for (int v = 0; v < NV; ++v) {
    int c4 = v * 256 + tid;
    float o0 = vals[v].x * scale, o1 = vals[v].y * scale,
          o2 = vals[v].z * scale, o3 = vals[v].w * scale;
    if constexpr (WEIGHT) {
      float4 wv = reinterpret_cast<const float4*>(w)[c4];
      o0 *= wv.x; o1 *= wv.y; o2 *= wv.z; o3 *= wv.w;
    }
    u16x4 ov = {f2b(o0), f2b(o1), f2b(o2), f2b(o3)};
    reinterpret_cast<u16x4*>(out + (size_t)row * width)[c4] = ov;
  }
}

// RMS bf16-in width 4096, silu, bf16 out
__global__ __launch_bounds__(256) void rms_silu_bf16_kernel(
    const u16* __restrict__ in, u16* __restrict__ out) {
  int row = blockIdx.x, tid = threadIdx.x;
  const u16* rp = in + (size_t)row * DFF;
  float f[16];
  float ss = 0.f;
#pragma unroll
  for (int v = 0; v < 2; ++v) {
    u16x8 c = reinterpret_cast<const u16x8*>(rp)[v * 256 + tid];
#pragma unroll
    for (int j = 0; j < 8; ++j) {
      float x = b2f((u16)c[j]);
      f[v * 8 + j] = x;
      ss += x * x;
    }
  }
  for (int off = 32; off; off >>= 1) ss += __shfl_down(ss, off, 64);
  __shared__ float wsum[4];
  if ((tid & 63) == 0) wsum[tid >> 6] = ss;
  __syncthreads();
  float tot = wsum[0] + wsum[1] + wsum[2] + wsum[3];
  float scale = rsqrtf(tot / (float)DFF + 1e-6f);
#pragma unroll
  for (int v = 0; v < 2; ++v) {
    u16x8 o;
#pragma unroll
    for (int j = 0; j < 8; ++j) {
      float x = f[v * 8 + j] * scale;
      x = x / (1.f + __expf(-x));
      o[j] = f2b(x);
    }
    reinterpret_cast<u16x8*>(out + (size_t)row * DFF)[v * 256 + tid] = o;
  }
}

// final: out = res + rms(in), width 1024, f32
__global__ __launch_bounds__(256) void rms_add_kernel(
    const float* __restrict__ in, const float* __restrict__ res,
    float* __restrict__ out) {
  int row = blockIdx.x, tid = threadIdx.x;
  float4 v = reinterpret_cast<const float4*>(in + (size_t)row * D_MODEL)[tid];
  float ss = v.x * v.x + v.y * v.y + v.z * v.z + v.w * v.w;
  for (int off = 32; off; off >>= 1) ss += __shfl_down(ss, off, 64);
  __shared__ float wsum[4];
  if ((tid & 63) == 0) wsum[tid >> 6] = ss;
  __syncthreads();
  float tot = wsum[0] + wsum[1] + wsum[2] + wsum[3];
  float scale = rsqrtf(tot / (float)D_MODEL + 1e-6f);
  float4 rv = reinterpret_cast<const float4*>(res + (size_t)row * D_MODEL)[tid];
  float4 o = make_float4(v.x * scale + rv.x, v.y * scale + rv.y,
                         v.z * scale + rv.z, v.w * scale + rv.w);
  reinterpret_cast<float4*>(out + (size_t)row * D_MODEL)[tid] = o;
}

// ---------------------------------------------------------------------------
// bf16 NT GEMM core, 2-phase double-buffered pipeline.
// C[128x128] = A[M,lda] * B[N,lda]^T over Kloop.  BK=32, 256 thr.
// OUT: 0 = bf16, 1 = f32 + res, 2 = f32 partial
// ---------------------------------------------------------------------------
template <int OUT>
__device__ inline void gemm_nt_body(const u16* A, const u16* B, void* Cv,
                                    const float* RES, int N, int lda, int Kloop,
                                    int row0, int col0) {
  __shared__ __align__(16) u16 As[2][128 * 32];
  __shared__ __align__(16) u16 Bs[2][128 * 32];
  int tid = threadIdx.x, lane = tid & 63, wid = tid >> 6;
  int wr = wid >> 1, wc = wid & 1;
  const f32x4 fz = {0.f, 0.f, 0.f, 0.f};
  f32x4 acc[4][4];
#pragma unroll
  for (int m = 0; m < 4; ++m)
#pragma unroll
    for (int n = 0; n < 4; ++n) acc[m][n] = fz;

  auto STAGE = [&](int buf, int k0) {
#pragma unroll
    for (int i = 0; i < 2; ++i) {
      int wl = wid * 2 + i;
      int row = wl * 16 + (lane >> 2);
      int col8 = ((lane & 3) ^ (row & 3)) * 8;
      gl_lds16(A + (size_t)(row0 + row) * lda + k0 + col8, &As[buf][wl * 512]);
      gl_lds16(B + (size_t)(col0 + row) * lda + k0 + col8, &Bs[buf][wl * 512]);
    }
  };

  STAGE(0, 0);
  int nk = Kloop >> 5;
  for (int j = 0; j < nk; ++j) {
    int cur = j & 1;
    if (j + 1 < nk) {
      STAGE(cur ^ 1, (j + 1) * 32);
      VMCNT(4);
    } else {
      VMCNT(0);
    }
    __syncthreads();
    bf16x8 af[4], bfr[4];
#pragma unroll
    for (int m = 0; m < 4; ++m) {
      int r = wr * 64 + m * 16 + (lane & 15);
      af[m] = *reinterpret_cast<const bf16x8*>(
          &As[cur][r * 32 + (((lane >> 4) ^ (r & 3)) << 3)]);
    }
#pragma unroll
    for (int n = 0; n < 4; ++n) {
      int r = wc * 64 + n * 16 + (lane & 15);
      bfr[n] = *reinterpret_cast<const bf16x8*>(
          &Bs[cur][r * 32 + (((lane >> 4) ^ (r & 3)) << 3)]);
    }
#pragma unroll
    for (int m = 0; m < 4; ++m)
#pragma unroll
      for (int n = 0; n < 4; ++n) acc[m][n] = MFMA16(af[m], bfr[n], acc[m][n]);
    __syncthreads();
  }
#pragma unroll
  for (int m = 0; m < 4; ++m)
#pragma unroll
    for (int n = 0; n < 4; ++n)
#pragma unroll
      for (int r = 0; r < 4; ++r) {
        int grow = row0 + wr * 64 + m * 16 + (lane >> 4) * 4 + r;
        int gcol = col0 + wc * 64 + n * 16 + (lane & 15);
        float v = acc[m][n][r];
        if constexpr (OUT == 0) {
          ((u16*)Cv)[(size_t)grow * N + gcol] = f2b(v);
        } else if constexpr (OUT == 1) {
          ((float*)Cv)[(size_t)grow * N + gcol] = v + RES[(size_t)grow * N + gcol];
        } else {
          ((float*)Cv)[(size_t)grow * N + gcol] = v;
        }
      }
}

__global__ __launch_bounds__(256) void gemm_qkv_kernel(
    const u16* __restrict__ A, const u16* Bq, const u16* Bk, const u16* Bv,
    u16* Cq, u16* Ck, u16* Cvp) {
  const u16* B = blockIdx.z == 0 ? Bq : (blockIdx.z == 1 ? Bk : Bv);
  u16* C = blockIdx.z == 0 ? Cq : (blockIdx.z == 1 ? Ck : Cvp);
  gemm_nt_body<0>(A, B, C, nullptr, D_MODEL, D_MODEL, D_MODEL,
                  blockIdx.y * 128, blockIdx.x * 128);
}
__global__ __launch_bounds__(256) void gemm_res_kernel(
    const u16* __restrict__ A, const u16* __restrict__ B, float* __restrict__ C,
    const float* __restrict__ RES) {
  gemm_nt_body<1>(A, B, C, RES, D_MODEL, D_MODEL, D_MODEL,
                  blockIdx.y * 128, blockIdx.x * 128);
}
// split-K down-proj: Cp[z][2048][256] partials, grid (2, 16, SPLIT)
__global__ __launch_bounds__(256) void gemm_splitk_kernel(
    const u16* __restrict__ A, const u16* __restrict__ B, float* __restrict__ Cp,
    int lda, int Kchunk) {
  int z = blockIdx.z;
  gemm_nt_body<2>(A + (size_t)z * Kchunk, B + (size_t)z * Kchunk,
                  Cp + (size_t)z * (T_LEN * 256), nullptr, 256, lda, Kchunk,
                  blockIdx.y * 128, blockIdx.x * 128);
}
__global__ __launch_bounds__(256) void reduce_conv_kernel(
    const float* __restrict__ part, u16* __restrict__ out, int n4, int nsplit) {
  int i = blockIdx.x * 256 + threadIdx.x;
  if (i >= n4) return;
  float4 a = reinterpret_cast<const float4*>(part)[i];
  for (int s = 1; s < nsplit; ++s) {
    float4 b = reinterpret_cast<const float4*>(part)[i + (size_t)s * n4];
    a.x += b.x; a.y += b.y; a.z += b.z; a.w += b.w;
  }
  u16x4 o = {f2b(a.x), f2b(a.y), f2b(a.z), f2b(a.w)};
  reinterpret_cast<u16x4*>(out)[i] = o;
}

// ---------------------------------------------------------------------------
// cache up-proj + product, h-pipelined: G = prod_h dot64(A[t][h], UP[h][o])
// ---------------------------------------------------------------------------
template <bool BF16_OUT>
__global__ __launch_bounds__(256) void cache_up_mfma(
    const u16* __restrict__ Acoef, const u16* __restrict__ UP,
    void* __restrict__ Gv, int N) {
  __shared__ __align__(16) u16 As[2][128 * 64];
  __shared__ __align__(16) u16 Bs[2][128 * 64];
  int tid = threadIdx.x, lane = tid & 63, wid = tid >> 6;
  int wr = wid >> 1, wc = wid & 1;
  int row0 = blockIdx.y * 128, col0 = blockIdx.x * 128;
  const f32x4 fz = {0.f, 0.f, 0.f, 0.f};
  f32x4 prod[4][4];
#pragma unroll
  for (int m = 0; m < 4; ++m)
#pragma unroll
    for (int n = 0; n < 4; ++n) prod[m][n] = fz + 1.f;

  auto STAGE = [&](int buf, int h) {
#pragma unroll
    for (int i = 0; i < 4; ++i) {
      int wl = wid * 4 + i;
      int row = wl * 8 + (lane >> 3);
      int col8 = ((lane & 7) ^ (row & 7)) * 8;
      gl_lds16(Acoef + (size_t)(row0 + row) * 256 + h * 64 + col8, &As[buf][wl * 512]);
      gl_lds16(UP + ((size_t)h * N + col0 + row) * 64 + col8, &Bs[buf][wl * 512]);
    }
  };

  STAGE(0, 0);
  for (int h = 0; h < 4; ++h) {
    int cur = h & 1;
    if (h < 3) {
      STAGE(cur ^ 1, h + 1);
      VMCNT(8);
    } else {
      VMCNT(0);
    }
    __syncthreads();
    f32x4 d[4][4];
#pragma unroll
    for (int m = 0; m < 4; ++m)
#pragma unroll
      for (int n = 0; n < 4; ++n) d[m][n] = fz;
#pragma unroll
    for (int kh = 0; kh < 2; ++kh) {
      bf16x8 af[4], bfr[4];
#pragma unroll
      for (int m = 0; m < 4; ++m) {
        int r = wr * 64 + m * 16 + (lane & 15);
        int slot = kh * 4 + (lane >> 4);
        af[m] = *reinterpret_cast<const bf16x8*>(
            &As[cur][r * 64 + ((slot ^ (r & 7)) << 3)]);
      }
#pragma unroll
      for (int n = 0; n < 4; ++n) {
        int r = wc * 64 + n * 16 + (lane & 15);
        int slot = kh * 4 + (lane >> 4);
        bfr[n] = *reinterpret_cast<const bf16x8*>(
            &Bs[cur][r * 64 + ((slot ^ (r & 7)) << 3)]);
      }
#pragma unroll
      for (int m = 0; m < 4; ++m)
#pragma unroll
        for (int n = 0; n < 4; ++n) d[m][n] = MFMA16(af[m], bfr[n], d[m][n]);
    }
#pragma unroll
    for (int m = 0; m < 4; ++m)
#pragma unroll
      for (int n = 0; n < 4; ++n) prod[m][n] *= d[m][n];
    __syncthreads();
  }
#pragma unroll
  for (int m = 0; m < 4; ++m)
#pragma unroll
    for (int n = 0; n < 4; ++n)
#pragma unroll
      for (int r = 0; r < 4; ++r) {
        int grow = row0 + wr * 64 + m * 16 + (lane >> 4) * 4 + r;
        int gcol = col0 + wc * 64 + n * 16 + (lane & 15);
        if constexpr (BF16_OUT)
          ((u16*)Gv)[(size_t)grow * N + gcol] = f2b(prod[m][n][r]);
        else
          ((float*)Gv)[(size_t)grow * N + gcol] = prod[m][n][r];
      }
}

// ---------------------------------------------------------------------------
// RoPE in place on bf16 q,k
// ---------------------------------------------------------------------------
__global__ __launch_bounds__(256) void rope_bf16_kernel(u16* __restrict__ q,
                                                        u16* __restrict__ k) {
  int t = blockIdx.x, tid = threadIdx.x;
  const float NEG = -0.28782313662425573f;  // -ln(10000)/32
#pragma unroll
  for (int u = 0; u < 2; ++u) {
    int p = tid + u * 256;
    int i = p & 31;
    int col = (p >> 5) * 64 + 2 * i;
    float ang = (float)t * __expf(NEG * (float)i);
    float sv, cv;
    __sincosf(ang, &sv, &cv);
    size_t idx = (size_t)t * D_MODEL + col;
    unsigned int* qp = reinterpret_cast<unsigned int*>(q + idx);
    unsigned int qv = *qp;
    float q1 = b2f(qv & 0xffff), q2 = b2f(qv >> 16);
    *qp = (unsigned int)f2b(q1 * cv - q2 * sv) |
          ((unsigned int)f2b(q1 * sv + q2 * cv) << 16);
    unsigned int* kp = reinterpret_cast<unsigned int*>(k + idx);
    unsigned int kv = *kp;
    float k1 = b2f(kv & 0xffff), k2 = b2f(kv >> 16);
    *kp = (unsigned int)f2b(k1 * cv - k2 * sv) |
          ((unsigned int)f2b(k1 * sv + k2 * cv) << 16);
  }
}

// ---------------------------------------------------------------------------
// MFMA flash attention, causal, swapped-QK^T + in-register P.
// 256 threads = 4 waves; QBLK=64 (16 q-rows/wave); KV tile 64, double-buffered
// with counted-vmcnt prefetch.  grid (T/64, NH), reversed for load balance.
// ---------------------------------------------------------------------------
__global__ __launch_bounds__(256) void attn_mfma_kernel(
    const u16* __restrict__ Q, const u16* __restrict__ Kb,
    const u16* __restrict__ VT, u16* __restrict__ O) {
  __shared__ __align__(16) u16 Ks[2][64 * 64];
  __shared__ __align__(16) u16 Vt[2][64 * 64];
  int tid = threadIdx.x, lane = tid & 63, wid = tid >> 6;
  int G = lane >> 4, ql = lane & 15;
  int head = blockIdx.y, hoff = head * 64;
  int qt = (int)gridDim.x - 1 - (int)blockIdx.x;
  int q0 = qt * 64;
  int qg = q0 + wid * 16 + ql;  // this lane's q-row (S^T layout)

  bf16x8 aq[2];
  {
    const u16* qp = Q + (size_t)qg * D_MODEL + hoff + G * 8;
    aq[0] = *reinterpret_cast<const bf16x8*>(qp);
    aq[1] = *reinterpret_cast<const bf16x8*>(qp + 32);
  }
  const f32x4 fz = {0.f, 0.f, 0.f, 0.f};
  f32x4 accO[4];
#pragma unroll
  for (int n = 0; n < 4; ++n) accO[n] = fz;
  float m_p = -INFINITY, l_p = 0.f;

  auto STAGE = [&](int buf, int j0) {
#pragma unroll
    for (int i = 0; i < 2; ++i) {
      int wl = wid * 2 + i;
      int row = wl * 8 + (lane >> 3);
      int col8 = ((lane & 7) ^ (row & 7)) * 8;
      gl_lds16(Kb + (size_t)(j0 + row) * D_MODEL + hoff + col8, &Ks[buf][wl * 512]);
      gl_lds16(VT + ((size_t)hoff + row) * T_LEN + j0 + col8, &Vt[buf][wl * 512]);
    }
  };

  int ntile = qt + 1;
  STAGE(0, 0);
  for (int jt = 0; jt < ntile; ++jt) {
    int j0 = jt * 64;
    int cur = jt & 1;
    if (jt + 1 < ntile) {
      STAGE(cur ^ 1, j0 + 64);
      VMCNT(4);
    } else {
      VMCNT(0);
    }
    __syncthreads();
    // ---- S^T = K Q^T : lane holds q=ql, k = n*16 + 4G + r
    f32x4 s[4];
#pragma unroll
    for (int n = 0; n < 4; ++n) s[n] = fz;
#pragma unroll
    for (int n = 0; n < 4; ++n) {
      int kr = n * 16 + ql;
#pragma unroll
      for (int h = 0; h < 2; ++h) {
        int slot = (h * 4 + G) ^ (kr & 7);
        bf16x8 bk = *reinterpret_cast<const bf16x8*>(&Ks[cur][kr * 64 + slot * 8]);
        s[n] = MFMA16(bk, aq[h], s[n]);
      }
    }
    bool diag = (jt == ntile - 1);
#pragma unroll
    for (int n = 0; n < 4; ++n)
#pragma unroll
      for (int r = 0; r < 4; ++r) {
        float sv = s[n][r] * 0.125f;
        if (diag && (j0 + n * 16 + 4 * G + r > qg)) sv = -INFINITY;
        s[n][r] = sv;
      }
    // ---- online softmax, lane-local in q
    float mx = s[0][0];
#pragma unroll
    for (int n = 0; n < 4; ++n)
#pragma unroll
      for (int r = 0; r < 4; ++r) mx = fmaxf(mx, s[n][r]);
    mx = fmaxf(mx, __shfl_xor(mx, 16, 64));
    mx = fmaxf(mx, __shfl_xor(mx, 32, 64));
    float mn = fmaxf(m_p, mx);
    float rsc = __expf(m_p - mn);
    m_p = mn;
    float ls = 0.f;
#pragma unroll
    for (int n = 0; n < 4; ++n)
#pragma unroll
      for (int r = 0; r < 4; ++r) {
        float p = __expf(s[n][r] - mn);
        s[n][r] = p;
        ls += p;
      }
    ls += __shfl_xor(ls, 16, 64);
    ls += __shfl_xor(ls, 32, 64);
    l_p = l_p * rsc + ls;
    // ---- pack P to bf16 pairs
    unsigned int w32[4][2];
#pragma unroll
    for (int n = 0; n < 4; ++n)
#pragma unroll
      for (int rr = 0; rr < 2; ++rr) {
        unsigned int pk;
        asm("v_cvt_pk_bf16_f32 %0, %1, %2"
            : "=v"(pk) : "v"(s[n][2 * rr]), "v"(s[n][2 * rr + 1]));
        w32[n][rr] = pk;
      }
    // ---- rescale accO (O rows are q = 4G + r)
    float rscx[4];
#pragma unroll
    for (int r = 0; r < 4; ++r) rscx[r] = __shfl(rsc, 4 * G + r, 64);
#pragma unroll
    for (int n = 0; n < 4; ++n)
#pragma unroll
      for (int r = 0; r < 4; ++r) accO[n][r] *= rscx[r];
    // ---- PV: assemble A-frag via cross-lane exchange
#pragma unroll
    for (int kh = 0; kh < 2; ++kh) {
      union { unsigned int w[4]; bf16x8 v; } ap;
#pragma unroll
      for (int w = 0; w < 4; ++w) {
        int src = ql + (((2 * G + (w >> 1)) & 3) << 4);
        unsigned int v0 = (unsigned int)__shfl((int)w32[2 * kh][w & 1], src, 64);
        unsigned int v1 = (unsigned int)__shfl((int)w32[2 * kh + 1][w & 1], src, 64);
        ap.w[w] = (G >> 1) ? v1 : v0;
      }
#pragma unroll
      for (int n = 0; n < 4; ++n) {
        int d = n * 16 + ql;
        int slot = (kh * 4 + G) ^ (d & 7);
        bf16x8 bv = *reinterpret_cast<const bf16x8*>(&Vt[cur][d * 64 + slot * 8]);
        accO[n] = MFMA16(ap.v, bv, accO[n]);
      }
    }
    __syncthreads();
  }
  float invl = 1.f / l_p;
  float linvx[4];
#pragma unroll
  for (int r = 0; r < 4; ++r) linvx[r] = __shfl(invl, 4 * G + r, 64);
#pragma unroll
  for (int n = 0; n < 4; ++n)
#pragma unroll
    for (int r = 0; r < 4; ++r) {
      int qrow = q0 + wid * 16 + 4 * G + r;
      O[(size_t)qrow * D_MODEL + hoff + n * 16 + ql] = f2b(accO[n][r] * linvx[r]);
    }
}

// ---------------------------------------------------------------------------
extern "C" void kernel_launch(void* const* d_in, const int* in_sizes, int n_in,
                              void* d_out, int out_size, void* d_ws, size_t ws_size,
                              hipStream_t stream) {
  (void)in_sizes; (void)n_in; (void)out_size; (void)ws_size;
  const float* x   = (const float*)d_in[0];
  const float* ln1 = (const float*)d_in[1];
  const float* ln2 = (const float*)d_in[2];
  const float* wq  = (const float*)d_in[3];
  const float* wk  = (const float*)d_in[4];
  const float* wv  = (const float*)d_in[5];
  const float* wo  = (const float*)d_in[6];
  const float* w1d = (const float*)d_in[7];
  const float* w1u = (const float*)d_in[8];
  const float* w2d = (const float*)d_in[9];
  const float* w2u = (const float*)d_in[10];
  float* out = (float*)d_out;
  char* ws = (char*)d_ws;
  const size_t HMB = 1ull << 19;  // 0.5 MB

  u16*   wqb  = (u16*)(ws + 0 * HMB);
  u16*   wkb  = (u16*)(ws + 4 * HMB);
  u16*   wvb  = (u16*)(ws + 8 * HMB);
  u16*   wob  = (u16*)(ws + 12 * HMB);
  u16*   w1ub = (u16*)(ws + 16 * HMB);   // 2 MB
  u16*   w2ub = (u16*)(ws + 20 * HMB);   // 0.5 MB
  u16*   wt1  = (u16*)(ws + 21 * HMB);   // 0.5 MB
  u16*   wt2  = (u16*)(ws + 22 * HMB);   // 2 MB -> ends 13 MB
  u16*   hb   = (u16*)(ws + 26 * HMB);   // 4 MB -> 17
  float* x1   = (float*)(ws + 34 * HMB); // 8 MB -> 25
  u16*   abuf = (u16*)(ws + 50 * HMB);   // 1 MB -> 26
  u16*   qb   = (u16*)(ws + 52 * HMB);   // 4 MB -> 30
  u16*   kb   = (u16*)(ws + 60 * HMB);   // 4 MB -> 34
  u16*   vb   = (u16*)(ws + 68 * HMB);   // 4 MB -> 38
  u16*   vtb  = (u16*)(ws + 76 * HMB);   // 4 MB -> 42
  u16*   aob  = (u16*)(ws + 84 * HMB);   // 4 MB -> 46
  u16*   g    = (u16*)(ws + 52 * HMB);   // 16 MB bf16, reuses qb..vtb
  float* g2   = (float*)(ws + 52 * HMB); // 8 MB f32, after g dead
  u16*   sb   = (u16*)(ws + 84 * HMB);   // 16 MB, reuses aob..
  float* part = (float*)(ws + 116 * HMB);// up to 16 MB

  dim3 b256(256);
  // weight prep (one merged dispatch + 2 transposes)
  prep_conv_kernel<<<dim3(1024, 1, 6), b256, 0, stream>>>(
      wq, wk, wv, wo, w1u, w2u, wqb, wkb, wvb, wob, w1ub, w2ub);
  tr_kernel<<<dim3(16, 4), b256, 0, stream>>>(w1d, wt1, 1024);
  tr_kernel<<<dim3(64, 4), b256, 0, stream>>>(w2d, wt2, 4096);
  // 1. h = rms(x)*ln1 -> bf16
  rms_bf16_kernel<1, true><<<T_LEN, b256, 0, stream>>>(x, ln1, hb, 1024);
  // 2. q,k,v
  gemm_qkv_kernel<<<dim3(8, 16, 3), b256, 0, stream>>>(hb, wqb, wkb, wvb, qb, kb, vb);
  // 3. rope + V transpose
  rope_bf16_kernel<<<T_LEN, b256, 0, stream>>>(qb, kb);
  vtrans_kernel<<<dim3(32, 16), b256, 0, stream>>>(vb, vtb);
  // 4. attention
  attn_mfma_kernel<<<dim3(T_LEN / 64, NH), b256, 0, stream>>>(qb, kb, vtb, aob);
  // 5. x1 = ao @ wo^T + x
  gemm_res_kernel<<<dim3(8, 16), b256, 0, stream>>>(aob, wob, x1, x);
  // 6. h2 = rms(x1)*ln2 -> bf16
  rms_bf16_kernel<1, true><<<T_LEN, b256, 0, stream>>>(x1, ln2, hb, 1024);
  // 7. down1 (split-K 4) -> abuf
  gemm_splitk_kernel<<<dim3(2, 16, 4), b256, 0, stream>>>(hb, wt1, part, 1024, 256);
  reduce_conv_kernel<<<512, b256, 0, stream>>>(part, abuf, 131072, 4);
  // 8. up1 + product -> g (bf16)
  cache_up_mfma<true><<<dim3(32, 16), b256, 0, stream>>>(abuf, w1ub, g, 4096);
  // 9. s = silu(rms(g)) -> sb
  rms_silu_bf16_kernel<<<T_LEN, b256, 0, stream>>>(g, sb);
  // 10. down2 (split-K 8) -> abuf
  gemm_splitk_kernel<<<dim3(2, 16, 8), b256, 0, stream>>>(sb, wt2, part, 4096, 512);
  reduce_conv_kernel<<<512, b256, 0, stream>>>(part, abuf, 131072, 8);
  // 11. up2 + product -> g2 (f32)
  cache_up_mfma<false><<<dim3(8, 16), b256, 0, stream>>>(abuf, w2ub, g2, 1024);
  // 12. out = x1 + rms(g2)
  rms_add_kernel<<<T_LEN, b256, 0, stream>>>(g2, x1, out);
}

// Round 5
// 283.206 us; speedup vs baseline: 1.0020x; 1.0020x over previous
//
#include <hip/hip_runtime.h>
#include <math.h>
#include <stdint.h>

#define T_LEN   2048
#define D_MODEL 1024
#define NH      16
#define DFF     4096

typedef __attribute__((ext_vector_type(8))) short bf16x8;
typedef __attribute__((ext_vector_type(4))) float f32x4;
typedef __attribute__((ext_vector_type(4))) unsigned short u16x4;
typedef __attribute__((ext_vector_type(8))) unsigned short u16x8;
typedef unsigned short u16;

__device__ inline u16 f2b(float x) {
  unsigned int u = __float_as_uint(x);
  unsigned int r = (u + 0x7fffu + ((u >> 16) & 1u)) >> 16;
  return (u16)r;
}
__device__ inline float b2f(u16 h) { return __uint_as_float(((unsigned int)h) << 16); }

typedef const __attribute__((address_space(1))) unsigned int* gas_t;
typedef __attribute__((address_space(3))) unsigned int* las_t;
__device__ inline void gl_lds16(const void* g, void* l) {
  __builtin_amdgcn_global_load_lds((gas_t)g, (las_t)l, 16, 0, 0);
}

#define MFMA16(a, b, c) __builtin_amdgcn_mfma_f32_16x16x32_bf16((a), (b), (c), 0, 0, 0)
#define VMCNT(N) asm volatile("s_waitcnt vmcnt(" #N ")" ::: "memory")

// ---------------------------------------------------------------------------
// merged weight prep: 6 convert segments in one dispatch.  grid (1024,1,6)
// ---------------------------------------------------------------------------
__global__ __launch_bounds__(256) void prep_conv_kernel(
    const float* s0, const float* s1, const float* s2, const float* s3,
    const float* s4, const float* s5,
    u16* d0, u16* d1, u16* d2, u16* d3, u16* d4, u16* d5) {
  int z = blockIdx.z;
  const float* s; u16* d; int n4;
  switch (z) {
    case 0: s = s0; d = d0; n4 = 262144; break;
    case 1: s = s1; d = d1; n4 = 262144; break;
    case 2: s = s2; d = d2; n4 = 262144; break;
    case 3: s = s3; d = d3; n4 = 262144; break;
    case 4: s = s4; d = d4; n4 = 262144; break;
    default: s = s5; d = d5; n4 = 65536; break;
  }
  int i = blockIdx.x * 256 + threadIdx.x;
  if (i < n4) {
    float4 v = reinterpret_cast<const float4*>(s)[i];
    u16x4 o = {f2b(v.x), f2b(v.y), f2b(v.z), f2b(v.w)};
    reinterpret_cast<u16x4*>(d)[i] = o;
  }
}

// ---------------------------------------------------------------------------
// transpose+convert: w[h][K][64] f32 -> wt[h*64+c][K] bf16.  grid (K/64, 4)
// ---------------------------------------------------------------------------
__global__ __launch_bounds__(256) void tr_kernel(
    const float* __restrict__ w, u16* __restrict__ wt, int K) {
  int k0 = blockIdx.x * 64, h = blockIdx.y;
  __shared__ float Ts[64][65];
  int tid = threadIdx.x;
#pragma unroll
  for (int i = 0; i < 4; ++i) {
    int idx = tid + i * 256;
    int r = idx >> 4, c4 = (idx & 15) * 4;
    float4 v = *reinterpret_cast<const float4*>(w + ((size_t)h * K + k0 + r) * 64 + c4);
    Ts[r][c4 + 0] = v.x; Ts[r][c4 + 1] = v.y; Ts[r][c4 + 2] = v.z; Ts[r][c4 + 3] = v.w;
  }
  __syncthreads();
#pragma unroll
  for (int i = 0; i < 4; ++i) {
    int idx = tid + i * 256;
    int c = idx >> 4, k4 = (idx & 15) * 4;
    u16x4 o = {f2b(Ts[k4 + 0][c]), f2b(Ts[k4 + 1][c]), f2b(Ts[k4 + 2][c]), f2b(Ts[k4 + 3][c])};
    *reinterpret_cast<u16x4*>(wt + (size_t)(h * 64 + c) * K + k0 + k4) = o;
  }
}

// ---------------------------------------------------------------------------
// V transpose: V[t][1024] bf16 -> VT[h*64+d][2048] bf16.  grid (T/64, 16)
// ---------------------------------------------------------------------------
__global__ __launch_bounds__(256) void vtrans_kernel(
    const u16* __restrict__ V, u16* __restrict__ VT) {
  __shared__ u16 Ts[64][72];
  int t0 = blockIdx.x * 64, h = blockIdx.y;
  int tid = threadIdx.x;
#pragma unroll
  for (int it = 0; it < 2; ++it) {
    int c = tid + it * 256;
    int t = c >> 3, d8 = (c & 7) * 8;
    *reinterpret_cast<u16x8*>(&Ts[t][d8]) =
        *reinterpret_cast<const u16x8*>(V + (size_t)(t0 + t) * D_MODEL + h * 64 + d8);
  }
  __syncthreads();
#pragma unroll
  for (int it = 0; it < 2; ++it) {
    int c = tid + it * 256;
    int d = c >> 3, t8 = (c & 7) * 8;
    u16x8 o;
#pragma unroll
    for (int j = 0; j < 8; ++j) o[j] = Ts[t8 + j][d];
    *reinterpret_cast<u16x8*>(VT + ((size_t)h * 64 + d) * T_LEN + t0 + t8) = o;
  }
}

// ---------------------------------------------------------------------------
// RMS f32-in -> bf16 (optional weight)
// ---------------------------------------------------------------------------
template <int NV, bool WEIGHT>
__global__ __launch_bounds__(256) void rms_bf16_kernel(
    const float* __restrict__ in, const float* __restrict__ w,
    u16* __restrict__ out, int width) {
  int row = blockIdx.x, tid = threadIdx.x;
  const float* rp = in + (size_t)row * width;
  float4 vals[NV];
  float ss = 0.f;
#pragma unroll
  for (int v = 0; v < NV; ++v) {
    vals[v] = reinterpret_cast<const float4*>(rp)[v * 256 + tid];
    ss += vals[v].x * vals[v].x + vals[v].y * vals[v].y +
          vals[v].z * vals[v].z + vals[v].w * vals[v].w;
  }
  for (int off = 32; off; off >>= 1) ss += __shfl_down(ss, off, 64);
  __shared__ float wsum[4];
  if ((tid & 63) == 0) wsum[tid >> 6] = ss;
  __syncthreads();
  float tot = wsum[0] + wsum[1] + wsum[2] + wsum[3];
  float scale = rsqrtf(tot / (float)width + 1e-6f);
#pragma unroll
  for (int v = 0; v < NV; ++v) {
    int c4 = v * 256 + tid;
    float o0 = vals[v].x * scale, o1 = vals[v].y * scale,
          o2 = vals[v].z * scale, o3 = vals[v].w * scale;
    if constexpr (WEIGHT) {
      float4 wv = reinterpret_cast<const float4*>(w)[c4];
      o0 *= wv.x; o1 *= wv.y; o2 *= wv.z; o3 *= wv.w;
    }
    u16x4 ov = {f2b(o0), f2b(o1), f2b(o2), f2b(o3)};
    reinterpret_cast<u16x4*>(out + (size_t)row * width)[c4] = ov;
  }
}

// RMS bf16-in width 4096, silu, bf16 out
__global__ __launch_bounds__(256) void rms_silu_bf16_kernel(
    const u16* __restrict__ in, u16* __restrict__ out) {
  int row = blockIdx.x, tid = threadIdx.x;
  const u16* rp = in + (size_t)row * DFF;
  float f[16];
  float ss = 0.f;
#pragma unroll
  for (int v = 0; v < 2; ++v) {
    u16x8 c = reinterpret_cast<const u16x8*>(rp)[v * 256 + tid];
#pragma unroll
    for (int j = 0; j < 8; ++j) {
      float x = b2f((u16)c[j]);
      f[v * 8 + j] = x;
      ss += x * x;
    }
  }
  for (int off = 32; off; off >>= 1) ss += __shfl_down(ss, off, 64);
  __shared__ float wsum[4];
  if ((tid & 63) == 0) wsum[tid >> 6] = ss;
  __syncthreads();
  float tot = wsum[0] + wsum[1] + wsum[2] + wsum[3];
  float scale = rsqrtf(tot / (float)DFF + 1e-6f);
#pragma unroll
  for (int v = 0; v < 2; ++v) {
    u16x8 o;
#pragma unroll
    for (int j = 0; j < 8; ++j) {
      float x = f[v * 8 + j] * scale;
      x = x / (1.f + __expf(-x));
      o[j] = f2b(x);
    }
    reinterpret_cast<u16x8*>(out + (size_t)row * DFF)[v * 256 + tid] = o;
  }
}

// final: out = res + rms(in), width 1024, f32
__global__ __launch_bounds__(256) void rms_add_kernel(
    const float* __restrict__ in, const float* __restrict__ res,
    float* __restrict__ out) {
  int row = blockIdx.x, tid = threadIdx.x;
  float4 v = reinterpret_cast<const float4*>(in + (size_t)row * D_MODEL)[tid];
  float ss = v.x * v.x + v.y * v.y + v.z * v.z + v.w * v.w;
  for (int off = 32; off; off >>= 1) ss += __shfl_down(ss, off, 64);
  __shared__ float wsum[4];
  if ((tid & 63) == 0) wsum[tid >> 6] = ss;
  __syncthreads();
  float tot = wsum[0] + wsum[1] + wsum[2] + wsum[3];
  float scale = rsqrtf(tot / (float)D_MODEL + 1e-6f);
  float4 rv = reinterpret_cast<const float4*>(res + (size_t)row * D_MODEL)[tid];
  float4 o = make_float4(v.x * scale + rv.x, v.y * scale + rv.y,
                         v.z * scale + rv.z, v.w * scale + rv.w);
  reinterpret_cast<float4*>(out + (size_t)row * D_MODEL)[tid] = o;
}

// ---------------------------------------------------------------------------
// bf16 NT GEMM core, 2-phase double-buffered pipeline.
// C[128x128] = A[M,lda] * B[N,lda]^T over Kloop.  BK=32, 256 thr.
// OUT: 0 = bf16, 1 = f32 + res, 2 = f32 partial
// ---------------------------------------------------------------------------
template <int OUT>
__device__ inline void gemm_nt_body(const u16* A, const u16* B, void* Cv,
                                    const float* RES, int N, int lda, int Kloop,
                                    int row0, int col0) {
  __shared__ __align__(16) u16 As[2][128 * 32];
  __shared__ __align__(16) u16 Bs[2][128 * 32];
  int tid = threadIdx.x, lane = tid & 63, wid = tid >> 6;
  int wr = wid >> 1, wc = wid & 1;
  const f32x4 fz = {0.f, 0.f, 0.f, 0.f};
  f32x4 acc[4][4];
#pragma unroll
  for (int m = 0; m < 4; ++m)
#pragma unroll
    for (int n = 0; n < 4; ++n) acc[m][n] = fz;

  auto STAGE = [&](int buf, int k0) {
#pragma unroll
    for (int i = 0; i < 2; ++i) {
      int wl = wid * 2 + i;
      int row = wl * 16 + (lane >> 2);
      int col8 = ((lane & 3) ^ (row & 3)) * 8;
      gl_lds16(A + (size_t)(row0 + row) * lda + k0 + col8, &As[buf][wl * 512]);
      gl_lds16(B + (size_t)(col0 + row) * lda + k0 + col8, &Bs[buf][wl * 512]);
    }
  };

  STAGE(0, 0);
  int nk = Kloop >> 5;
  for (int j = 0; j < nk; ++j) {
    int cur = j & 1;
    if (j + 1 < nk) {
      STAGE(cur ^ 1, (j + 1) * 32);
      VMCNT(4);
    } else {
      VMCNT(0);
    }
    __syncthreads();
    bf16x8 af[4], bfr[4];
#pragma unroll
    for (int m = 0; m < 4; ++m) {
      int r = wr * 64 + m * 16 + (lane & 15);
      af[m] = *reinterpret_cast<const bf16x8*>(
          &As[cur][r * 32 + (((lane >> 4) ^ (r & 3)) << 3)]);
    }
#pragma unroll
    for (int n = 0; n < 4; ++n) {
      int r = wc * 64 + n * 16 + (lane & 15);
      bfr[n] = *reinterpret_cast<const bf16x8*>(
          &Bs[cur][r * 32 + (((lane >> 4) ^ (r & 3)) << 3)]);
    }
#pragma unroll
    for (int m = 0; m < 4; ++m)
#pragma unroll
      for (int n = 0; n < 4; ++n) acc[m][n] = MFMA16(af[m], bfr[n], acc[m][n]);
    __syncthreads();
  }
#pragma unroll
  for (int m = 0; m < 4; ++m)
#pragma unroll
    for (int n = 0; n < 4; ++n)
#pragma unroll
      for (int r = 0; r < 4; ++r) {
        int grow = row0 + wr * 64 + m * 16 + (lane >> 4) * 4 + r;
        int gcol = col0 + wc * 64 + n * 16 + (lane & 15);
        float v = acc[m][n][r];
        if constexpr (OUT == 0) {
          ((u16*)Cv)[(size_t)grow * N + gcol] = f2b(v);
        } else if constexpr (OUT == 1) {
          ((float*)Cv)[(size_t)grow * N + gcol] = v + RES[(size_t)grow * N + gcol];
        } else {
          ((float*)Cv)[(size_t)grow * N + gcol] = v;
        }
      }
}

__global__ __launch_bounds__(256) void gemm_qkv_kernel(
    const u16* __restrict__ A, const u16* Bq, const u16* Bk, const u16* Bv,
    u16* Cq, u16* Ck, u16* Cvp) {
  const u16* B = blockIdx.z == 0 ? Bq : (blockIdx.z == 1 ? Bk : Bv);
  u16* C = blockIdx.z == 0 ? Cq : (blockIdx.z == 1 ? Ck : Cvp);
  gemm_nt_body<0>(A, B, C, nullptr, D_MODEL, D_MODEL, D_MODEL,
                  blockIdx.y * 128, blockIdx.x * 128);
}
__global__ __launch_bounds__(256) void gemm_res_kernel(
    const u16* __restrict__ A, const u16* __restrict__ B, float* __restrict__ C,
    const float* __restrict__ RES) {
  gemm_nt_body<1>(A, B, C, RES, D_MODEL, D_MODEL, D_MODEL,
                  blockIdx.y * 128, blockIdx.x * 128);
}
// split-K down-proj: Cp[z][2048][256] partials, grid (2, 16, SPLIT)
__global__ __launch_bounds__(256) void gemm_splitk_kernel(
    const u16* __restrict__ A, const u16* __restrict__ B, float* __restrict__ Cp,
    int lda, int Kchunk) {
  int z = blockIdx.z;
  gemm_nt_body<2>(A + (size_t)z * Kchunk, B + (size_t)z * Kchunk,
                  Cp + (size_t)z * (T_LEN * 256), nullptr, 256, lda, Kchunk,
                  blockIdx.y * 128, blockIdx.x * 128);
}
__global__ __launch_bounds__(256) void reduce_conv_kernel(
    const float* __restrict__ part, u16* __restrict__ out, int n4, int nsplit) {
  int i = blockIdx.x * 256 + threadIdx.x;
  if (i >= n4) return;
  float4 a = reinterpret_cast<const float4*>(part)[i];
  for (int s = 1; s < nsplit; ++s) {
    float4 b = reinterpret_cast<const float4*>(part)[i + (size_t)s * n4];
    a.x += b.x; a.y += b.y; a.z += b.z; a.w += b.w;
  }
  u16x4 o = {f2b(a.x), f2b(a.y), f2b(a.z), f2b(a.w)};
  reinterpret_cast<u16x4*>(out)[i] = o;
}

// ---------------------------------------------------------------------------
// cache up-proj + product, h-pipelined: G = prod_h dot64(A[t][h], UP[h][o])
// ---------------------------------------------------------------------------
template <bool BF16_OUT>
__global__ __launch_bounds__(256) void cache_up_mfma(
    const u16* __restrict__ Acoef, const u16* __restrict__ UP,
    void* __restrict__ Gv, int N) {
  __shared__ __align__(16) u16 As[2][128 * 64];
  __shared__ __align__(16) u16 Bs[2][128 * 64];
  int tid = threadIdx.x, lane = tid & 63, wid = tid >> 6;
  int wr = wid >> 1, wc = wid & 1;
  int row0 = blockIdx.y * 128, col0 = blockIdx.x * 128;
  const f32x4 fz = {0.f, 0.f, 0.f, 0.f};
  f32x4 prod[4][4];
#pragma unroll
  for (int m = 0; m < 4; ++m)
#pragma unroll
    for (int n = 0; n < 4; ++n) prod[m][n] = fz + 1.f;

  auto STAGE = [&](int buf, int h) {
#pragma unroll
    for (int i = 0; i < 4; ++i) {
      int wl = wid * 4 + i;
      int row = wl * 8 + (lane >> 3);
      int col8 = ((lane & 7) ^ (row & 7)) * 8;
      gl_lds16(Acoef + (size_t)(row0 + row) * 256 + h * 64 + col8, &As[buf][wl * 512]);
      gl_lds16(UP + ((size_t)h * N + col0 + row) * 64 + col8, &Bs[buf][wl * 512]);
    }
  };

  STAGE(0, 0);
  for (int h = 0; h < 4; ++h) {
    int cur = h & 1;
    if (h < 3) {
      STAGE(cur ^ 1, h + 1);
      VMCNT(8);
    } else {
      VMCNT(0);
    }
    __syncthreads();
    f32x4 d[4][4];
#pragma unroll
    for (int m = 0; m < 4; ++m)
#pragma unroll
      for (int n = 0; n < 4; ++n) d[m][n] = fz;
#pragma unroll
    for (int kh = 0; kh < 2; ++kh) {
      bf16x8 af[4], bfr[4];
#pragma unroll
      for (int m = 0; m < 4; ++m) {
        int r = wr * 64 + m * 16 + (lane & 15);
        int slot = kh * 4 + (lane >> 4);
        af[m] = *reinterpret_cast<const bf16x8*>(
            &As[cur][r * 64 + ((slot ^ (r & 7)) << 3)]);
      }
#pragma unroll
      for (int n = 0; n < 4; ++n) {
        int r = wc * 64 + n * 16 + (lane & 15);
        int slot = kh * 4 + (lane >> 4);
        bfr[n] = *reinterpret_cast<const bf16x8*>(
            &Bs[cur][r * 64 + ((slot ^ (r & 7)) << 3)]);
      }
#pragma unroll
      for (int m = 0; m < 4; ++m)
#pragma unroll
        for (int n = 0; n < 4; ++n) d[m][n] = MFMA16(af[m], bfr[n], d[m][n]);
    }
#pragma unroll
    for (int m = 0; m < 4; ++m)
#pragma unroll
      for (int n = 0; n < 4; ++n) prod[m][n] *= d[m][n];
    __syncthreads();
  }
#pragma unroll
  for (int m = 0; m < 4; ++m)
#pragma unroll
    for (int n = 0; n < 4; ++n)
#pragma unroll
      for (int r = 0; r < 4; ++r) {
        int grow = row0 + wr * 64 + m * 16 + (lane >> 4) * 4 + r;
        int gcol = col0 + wc * 64 + n * 16 + (lane & 15);
        if constexpr (BF16_OUT)
          ((u16*)Gv)[(size_t)grow * N + gcol] = f2b(prod[m][n][r]);
        else
          ((float*)Gv)[(size_t)grow * N + gcol] = prod[m][n][r];
      }
}

// ---------------------------------------------------------------------------
// RoPE in place on bf16 q,k
// ---------------------------------------------------------------------------
__global__ __launch_bounds__(256) void rope_bf16_kernel(u16* __restrict__ q,
                                                        u16* __restrict__ k) {
  int t = blockIdx.x, tid = threadIdx.x;
  const float NEG = -0.28782313662425573f;  // -ln(10000)/32
#pragma unroll
  for (int u = 0; u < 2; ++u) {
    int p = tid + u * 256;
    int i = p & 31;
    int col = (p >> 5) * 64 + 2 * i;
    float ang = (float)t * __expf(NEG * (float)i);
    float sv, cv;
    __sincosf(ang, &sv, &cv);
    size_t idx = (size_t)t * D_MODEL + col;
    unsigned int* qp = reinterpret_cast<unsigned int*>(q + idx);
    unsigned int qv = *qp;
    float q1 = b2f(qv & 0xffff), q2 = b2f(qv >> 16);
    *qp = (unsigned int)f2b(q1 * cv - q2 * sv) |
          ((unsigned int)f2b(q1 * sv + q2 * cv) << 16);
    unsigned int* kp = reinterpret_cast<unsigned int*>(k + idx);
    unsigned int kv = *kp;
    float k1 = b2f(kv & 0xffff), k2 = b2f(kv >> 16);
    *kp = (unsigned int)f2b(k1 * cv - k2 * sv) |
          ((unsigned int)f2b(k1 * sv + k2 * cv) << 16);
  }
}

// ---------------------------------------------------------------------------
// Split-KV MFMA flash attention, causal, swapped-QK^T + in-register P.
// grid (T/64, NH, 4): block = (q-tile of 64 rows, head, KV-chunk of 512).
// Writes unnormalized O partial (bf16) + per-row (m, l) to workspace.
// 256 thr = 4 waves; KV tile 64 double-buffered, counted vmcnt.
// ---------------------------------------------------------------------------
#define KVCHUNK_TILES 8
__global__ __launch_bounds__(256) void attn_mfma_kernel(
    const u16* __restrict__ Q, const u16* __restrict__ Kb,
    const u16* __restrict__ VT, u16* __restrict__ Opart,
    float* __restrict__ mlb) {
  int qt = blockIdx.x, c = blockIdx.z;
  if (c * KVCHUNK_TILES > qt) return;   // chunk beyond diagonal: no work
  __shared__ __align__(16) u16 Ks[2][64 * 64];
  __shared__ __align__(16) u16 Vt[2][64 * 64];
  int tid = threadIdx.x, lane = tid & 63, wid = tid >> 6;
  int G = lane >> 4, ql = lane & 15;
  int head = blockIdx.y, hoff = head * 64;
  int q0 = qt * 64;
  int qg = q0 + wid * 16 + ql;  // this lane's q-row (S^T layout)

  bf16x8 aq[2];
  {
    const u16* qp = Q + (size_t)qg * D_MODEL + hoff + G * 8;
    aq[0] = *reinterpret_cast<const bf16x8*>(qp);
    aq[1] = *reinterpret_cast<const bf16x8*>(qp + 32);
  }
  const f32x4 fz = {0.f, 0.f, 0.f, 0.f};
  f32x4 accO[4];
#pragma unroll
  for (int n = 0; n < 4; ++n) accO[n] = fz;
  float m_p = -INFINITY, l_p = 0.f;

  auto STAGE = [&](int buf, int j0) {
#pragma unroll
    for (int i = 0; i < 2; ++i) {
      int wl = wid * 2 + i;
      int row = wl * 8 + (lane >> 3);
      int col8 = ((lane & 7) ^ (row & 7)) * 8;
      gl_lds16(Kb + (size_t)(j0 + row) * D_MODEL + hoff + col8, &Ks[buf][wl * 512]);
      gl_lds16(VT + ((size_t)hoff + row) * T_LEN + j0 + col8, &Vt[buf][wl * 512]);
    }
  };

  int t0 = c * KVCHUNK_TILES;
  int tend = min(t0 + KVCHUNK_TILES, qt + 1);
  int ntile = tend - t0;
  STAGE(0, t0 * 64);
  for (int jl = 0; jl < ntile; ++jl) {
    int jt = t0 + jl;
    int j0 = jt * 64;
    int cur = jl & 1;
    if (jl + 1 < ntile) {
      STAGE(cur ^ 1, j0 + 64);
      VMCNT(4);
    } else {
      VMCNT(0);
    }
    __syncthreads();
    // ---- S^T = K Q^T : lane holds q=ql, k = n*16 + 4G + r
    f32x4 s[4];
#pragma unroll
    for (int n = 0; n < 4; ++n) s[n] = fz;
#pragma unroll
    for (int n = 0; n < 4; ++n) {
      int kr = n * 16 + ql;
#pragma unroll
      for (int h = 0; h < 2; ++h) {
        int slot = (h * 4 + G) ^ (kr & 7);
        bf16x8 bk = *reinterpret_cast<const bf16x8*>(&Ks[cur][kr * 64 + slot * 8]);
        s[n] = MFMA16(bk, aq[h], s[n]);
      }
    }
    bool diag = (jt == qt);
#pragma unroll
    for (int n = 0; n < 4; ++n)
#pragma unroll
      for (int r = 0; r < 4; ++r) {
        float sv = s[n][r] * 0.125f;
        if (diag && (j0 + n * 16 + 4 * G + r > qg)) sv = -INFINITY;
        s[n][r] = sv;
      }
    // ---- online softmax, lane-local in q (tree reductions)
    float m4[4];
#pragma unroll
    for (int n = 0; n < 4; ++n)
      m4[n] = fmaxf(fmaxf(s[n][0], s[n][1]), fmaxf(s[n][2], s[n][3]));
    float mx = fmaxf(fmaxf(m4[0], m4[1]), fmaxf(m4[2], m4[3]));
    mx = fmaxf(mx, __shfl_xor(mx, 16, 64));
    mx = fmaxf(mx, __shfl_xor(mx, 32, 64));
    float mn = fmaxf(m_p, mx);
    float sub = fmaxf(mn, -1e30f);    // guard (bit-identical when mn finite)
    float rsc = __expf(m_p - sub);
    m_p = mn;
    float s4[4];
#pragma unroll
    for (int n = 0; n < 4; ++n) {
#pragma unroll
      for (int r = 0; r < 4; ++r) s[n][r] = __expf(s[n][r] - sub);
      s4[n] = (s[n][0] + s[n][1]) + (s[n][2] + s[n][3]);
    }
    float ls = (s4[0] + s4[1]) + (s4[2] + s4[3]);
    ls += __shfl_xor(ls, 16, 64);
    ls += __shfl_xor(ls, 32, 64);
    l_p = l_p * rsc + ls;
    // ---- pack P to bf16 pairs
    unsigned int w32[4][2];
#pragma unroll
    for (int n = 0; n < 4; ++n)
#pragma unroll
      for (int rr = 0; rr < 2; ++rr) {
        unsigned int pk;
        asm("v_cvt_pk_bf16_f32 %0, %1, %2"
            : "=v"(pk) : "v"(s[n][2 * rr]), "v"(s[n][2 * rr + 1]));
        w32[n][rr] = pk;
      }
    // ---- rescale accO (O rows are q = 4G + r)
    float rscx[4];
#pragma unroll
    for (int r = 0; r < 4; ++r) rscx[r] = __shfl(rsc, 4 * G + r, 64);
#pragma unroll
    for (int n = 0; n < 4; ++n)
#pragma unroll
      for (int r = 0; r < 4; ++r) accO[n][r] *= rscx[r];
    // ---- PV: assemble A-frag via cross-lane exchange
#pragma unroll
    for (int kh = 0; kh < 2; ++kh) {
      union { unsigned int w[4]; bf16x8 v; } ap;
#pragma unroll
      for (int w = 0; w < 4; ++w) {
        int src = ql + (((2 * G + (w >> 1)) & 3) << 4);
        unsigned int v0 = (unsigned int)__shfl((int)w32[2 * kh][w & 1], src, 64);
        unsigned int v1 = (unsigned int)__shfl((int)w32[2 * kh + 1][w & 1], src, 64);
        ap.w[w] = (G >> 1) ? v1 : v0;
      }
#pragma unroll
      for (int n = 0; n < 4; ++n) {
        int d = n * 16 + ql;
        int slot = (kh * 4 + G) ^ (d & 7);
        bf16x8 bv = *reinterpret_cast<const bf16x8*>(&Vt[cur][d * 64 + slot * 8]);
        accO[n] = MFMA16(ap.v, bv, accO[n]);
      }
    }
    __syncthreads();
  }
  // ---- write unnormalized partials
#pragma unroll
  for (int n = 0; n < 4; ++n)
#pragma unroll
    for (int r = 0; r < 4; ++r) {
      int qrow = q0 + wid * 16 + 4 * G + r;
      Opart[((size_t)c * T_LEN + qrow) * D_MODEL + hoff + n * 16 + ql] =
          f2b(accO[n][r]);
    }
  if (G == 0) {
    int qrow = q0 + wid * 16 + ql;
    mlb[(c * NH + head) * T_LEN + qrow] = m_p;
    mlb[4 * NH * T_LEN + (c * NH + head) * T_LEN + qrow] = l_p;
  }
}

// ---------------------------------------------------------------------------
// attn combine: merge <=4 chunk partials per (head, q-row) -> bf16 O
// grid (T_LEN), 256 thr: thread = (head = tid>>4, 4 dims)
// ---------------------------------------------------------------------------
__global__ __launch_bounds__(256) void attn_combine_kernel(
    const u16* __restrict__ Opart, const float* __restrict__ mlb,
    u16* __restrict__ O) {
  int t = blockIdx.x, tid = threadIdx.x;
  int head = tid >> 4, d4 = (tid & 15) * 4;
  int nc = t / (KVCHUNK_TILES * 64) + 1;
  float mv[4];
  float ms = -INFINITY;
  for (int c = 0; c < nc; ++c) {
    mv[c] = mlb[(c * NH + head) * T_LEN + t];
    ms = fmaxf(ms, mv[c]);
  }
  float lsum = 0.f;
  float o0 = 0.f, o1 = 0.f, o2 = 0.f, o3 = 0.f;
  for (int c = 0; c < nc; ++c) {
    float w = __expf(mv[c] - ms);
    lsum += w * mlb[4 * NH * T_LEN + (c * NH + head) * T_LEN + t];
    u16x4 op = *reinterpret_cast<const u16x4*>(
        Opart + ((size_t)c * T_LEN + t) * D_MODEL + head * 64 + d4);
    o0 += w * b2f(op[0]); o1 += w * b2f(op[1]);
    o2 += w * b2f(op[2]); o3 += w * b2f(op[3]);
  }
  float inv = 1.f / lsum;
  u16x4 ov = {f2b(o0 * inv), f2b(o1 * inv), f2b(o2 * inv), f2b(o3 * inv)};
  *reinterpret_cast<u16x4*>(O + (size_t)t * D_MODEL + head * 64 + d4) = ov;
}

// ---------------------------------------------------------------------------
extern "C" void kernel_launch(void* const* d_in, const int* in_sizes, int n_in,
                              void* d_out, int out_size, void* d_ws, size_t ws_size,
                              hipStream_t stream) {
  (void)in_sizes; (void)n_in; (void)out_size; (void)ws_size;
  const float* x   = (const float*)d_in[0];
  const float* ln1 = (const float*)d_in[1];
  const float* ln2 = (const float*)d_in[2];
  const float* wq  = (const float*)d_in[3];
  const float* wk  = (const float*)d_in[4];
  const float* wv  = (const float*)d_in[5];
  const float* wo  = (const float*)d_in[6];
  const float* w1d = (const float*)d_in[7];
  const float* w1u = (const float*)d_in[8];
  const float* w2d = (const float*)d_in[9];
  const float* w2u = (const float*)d_in[10];
  float* out = (float*)d_out;
  char* ws = (char*)d_ws;
  const size_t HMB = 1ull << 19;  // 0.5 MB

  u16*   wqb  = (u16*)(ws + 0 * HMB);
  u16*   wkb  = (u16*)(ws + 4 * HMB);
  u16*   wvb  = (u16*)(ws + 8 * HMB);
  u16*   wob  = (u16*)(ws + 12 * HMB);
  u16*   w1ub = (u16*)(ws + 16 * HMB);   // 2 MB
  u16*   w2ub = (u16*)(ws + 20 * HMB);   // 0.5 MB
  u16*   wt1  = (u16*)(ws + 21 * HMB);   // 0.5 MB
  u16*   wt2  = (u16*)(ws + 22 * HMB);   // 2 MB -> ends 13 MB
  u16*   hb   = (u16*)(ws + 26 * HMB);   // 4 MB -> 17
  float* x1   = (float*)(ws + 34 * HMB); // 8 MB -> 25
  u16*   abuf = (u16*)(ws + 50 * HMB);   // 1 MB -> 26
  u16*   qb   = (u16*)(ws + 52 * HMB);   // 4 MB -> 30
  u16*   kb   = (u16*)(ws + 60 * HMB);   // 4 MB -> 34
  u16*   vb   = (u16*)(ws + 68 * HMB);   // 4 MB -> 38
  u16*   vtb  = (u16*)(ws + 76 * HMB);   // 4 MB -> 42
  u16*   aob  = (u16*)(ws + 84 * HMB);   // 4 MB -> 46
  u16*   g    = (u16*)(ws + 52 * HMB);   // 16 MB bf16, reuses qb..vtb
  float* g2   = (float*)(ws + 52 * HMB); // 8 MB f32, after g dead
  u16*   sb   = (u16*)(ws + 84 * HMB);   // 16 MB, reuses aob..
  float* part = (float*)(ws + 116 * HMB);// 16 MB (58..74) - splitk partials
  u16*   opart= (u16*)(ws + 116 * HMB);  // 16 MB - attn partials (disjoint in time)
  float* mlb  = (float*)(ws + 148 * HMB);// 1 MB (74..75) - attn m/l

  dim3 b256(256);
  // weight prep (one merged dispatch + 2 transposes)
  prep_conv_kernel<<<dim3(1024, 1, 6), b256, 0, stream>>>(
      wq, wk, wv, wo, w1u, w2u, wqb, wkb, wvb, wob, w1ub, w2ub);
  tr_kernel<<<dim3(16, 4), b256, 0, stream>>>(w1d, wt1, 1024);
  tr_kernel<<<dim3(64, 4), b256, 0, stream>>>(w2d, wt2, 4096);
  // 1. h = rms(x)*ln1 -> bf16
  rms_bf16_kernel<1, true><<<T_LEN, b256, 0, stream>>>(x, ln1, hb, 1024);
  // 2. q,k,v
  gemm_qkv_kernel<<<dim3(8, 16, 3), b256, 0, stream>>>(hb, wqb, wkb, wvb, qb, kb, vb);
  // 3. rope + V transpose
  rope_bf16_kernel<<<T_LEN, b256, 0, stream>>>(qb, kb);
  vtrans_kernel<<<dim3(32, 16), b256, 0, stream>>>(vb, vtb);
  // 4. attention (split-KV) + combine
  attn_mfma_kernel<<<dim3(T_LEN / 64, NH, 4), b256, 0, stream>>>(qb, kb, vtb,
                                                                 opart, mlb);
  attn_combine_kernel<<<T_LEN, b256, 0, stream>>>(opart, mlb, aob);
  // 5. x1 = ao @ wo^T + x
  gemm_res_kernel<<<dim3(8, 16), b256, 0, stream>>>(aob, wob, x1, x);
  // 6. h2 = rms(x1)*ln2 -> bf16
  rms_bf16_kernel<1, true><<<T_LEN, b256, 0, stream>>>(x1, ln2, hb, 1024);
  // 7. down1 (split-K 4) -> abuf
  gemm_splitk_kernel<<<dim3(2, 16, 4), b256, 0, stream>>>(hb, wt1, part, 1024, 256);
  reduce_conv_kernel<<<512, b256, 0, stream>>>(part, abuf, 131072, 4);
  // 8. up1 + product -> g (bf16)
  cache_up_mfma<true><<<dim3(32, 16), b256, 0, stream>>>(abuf, w1ub, g, 4096);
  // 9. s = silu(rms(g)) -> sb
  rms_silu_bf16_kernel<<<T_LEN, b256, 0, stream>>>(g, sb);
  // 10. down2 (split-K 8) -> abuf
  gemm_splitk_kernel<<<dim3(2, 16, 8), b256, 0, stream>>>(sb, wt2, part, 4096, 512);
  reduce_conv_kernel<<<512, b256, 0, stream>>>(part, abuf, 131072, 8);
  // 11. up2 + product -> g2 (f32)
  cache_up_mfma<false><<<dim3(8, 16), b256, 0, stream>>>(abuf, w2ub, g2, 1024);
  // 12. out = x1 + rms(g2)
  rms_add_kernel<<<T_LEN, b256, 0, stream>>>(g2, x1, out);
}